// Round 6
// baseline (157.238 us; speedup 1.0000x reference)
//
#include <hip/hip_runtime.h>

// Mean aggregator: out[n,:] = (1/K) * sum_k weight[idx[n,k],:]
// N = 100000 nodes, K = 10 neighbors, D = 128 feat (fp32).
//
// R6: cross-node software pipeline (falsification test for the
// service-rate-ceiling hypothesis). Persistent slots (32 lanes/node,
// grid-stride); per iteration:
//   1. issue idx loads for NEXT node (5x dwordx2, inline asm)
//   2. s_waitcnt vmcnt(5)  -> current gathers done, idx still in flight
//   3. reduce + nt store current node
//   4. s_waitcnt vmcnt(1)  -> idx data ready, store still in flight
//   5. issue 10 gathers for next node
// The vmcnt pipe never drains to empty; idx latency hides under gathers.
// All VMEM via inline asm + manual counted waits; sched_barrier(0) after
// every waitcnt (rule #18: reg-only consumers get hoisted past asm waits).

#define AGG_K 10
#define AGG_D 128

typedef float f32x4 __attribute__((ext_vector_type(4)));
typedef int   i32x2 __attribute__((ext_vector_type(2)));

__global__ __launch_bounds__(256) void Aggregator_26439818674919_kernel(
    const float* __restrict__ weight,
    const int* __restrict__ nidx,
    float* __restrict__ out,
    int n_nodes, int nslots) {
  const int tid  = blockIdx.x * 256 + threadIdx.x;
  int cur = tid >> 5;          // starting node for this 32-lane slot
  const int lane = tid & 31;
  if (cur >= n_nodes) return;

  const unsigned lane_off = (unsigned)(lane * 4);
  i32x2 I0, I1, I2, I3, I4;
  f32x4 v0, v1, v2, v3, v4, v5, v6, v7, v8, v9;

  // nidx + node*10 is 8B-aligned (40B stride) -> dwordx2 ok.
#define AGG_IDX_LD(node_)                                                    \
  {                                                                          \
    const int* ip_ = nidx + (size_t)(node_) * AGG_K;                         \
    asm volatile("global_load_dwordx2 %0, %1, off" : "=v"(I0) : "v"(ip_));   \
    asm volatile("global_load_dwordx2 %0, %1, off" : "=v"(I1) : "v"(ip_+2)); \
    asm volatile("global_load_dwordx2 %0, %1, off" : "=v"(I2) : "v"(ip_+4)); \
    asm volatile("global_load_dwordx2 %0, %1, off" : "=v"(I3) : "v"(ip_+6)); \
    asm volatile("global_load_dwordx2 %0, %1, off" : "=v"(I4) : "v"(ip_+8)); \
  }

#define AGG_GATHER(ii, dst)                                                  \
  {                                                                          \
    const float* p_ = weight + ((unsigned)(ii) * AGG_D + lane_off);          \
    asm volatile("global_load_dwordx4 %0, %1, off" : "=v"(dst) : "v"(p_));   \
  }
#define AGG_GATHER_ALL()                                                     \
  AGG_GATHER(I0[0], v0) AGG_GATHER(I0[1], v1) AGG_GATHER(I1[0], v2)          \
  AGG_GATHER(I1[1], v3) AGG_GATHER(I2[0], v4) AGG_GATHER(I2[1], v5)          \
  AGG_GATHER(I3[0], v6) AGG_GATHER(I3[1], v7) AGG_GATHER(I4[0], v8)          \
  AGG_GATHER(I4[1], v9)

  // Prologue: first node's idx -> gathers in flight.
  AGG_IDX_LD(cur);
  asm volatile("s_waitcnt vmcnt(0)" ::: "memory");
  __builtin_amdgcn_sched_barrier(0);
  AGG_GATHER_ALL();

  for (;;) {
    const int nxt = cur + nslots;
    // Dummy reload of cur's idx on the last trip keeps the vmcnt
    // schedule identical for all iterations.
    AGG_IDX_LD(nxt < n_nodes ? nxt : cur);
    // outstanding: G_cur(10) then I(5) [+ older store, already retired by
    // this wait]; vmcnt(5) -> all 10 gathers landed, idx still flying.
    asm volatile("s_waitcnt vmcnt(5)" ::: "memory");
    __builtin_amdgcn_sched_barrier(0);

    f32x4 acc = ((v0 + v1) + (v2 + v3)) +
                (((v4 + v5) + (v6 + v7)) + (v8 + v9));
    acc *= (1.0f / AGG_K);
    float* op_ = out + (size_t)cur * AGG_D + lane_off;
    asm volatile("global_store_dwordx4 %0, %1, off nt"
                 :: "v"(op_), "v"(acc) : "memory");

    if (nxt >= n_nodes) break;

    // outstanding: I(5) then S(1); vmcnt(1) -> idx data ready, store may
    // still be in flight (never drain to empty).
    asm volatile("s_waitcnt vmcnt(1)" ::: "memory");
    __builtin_amdgcn_sched_barrier(0);
    cur = nxt;
    AGG_GATHER_ALL();
  }
}

extern "C" void kernel_launch(void* const* d_in, const int* in_sizes, int n_in,
                              void* d_out, int out_size, void* d_ws, size_t ws_size,
                              hipStream_t stream) {
  const float* weight = (const float*)d_in[0];
  const int*   nidx   = (const int*)d_in[1];
  float*       out    = (float*)d_out;

  const int n_nodes = in_sizes[1] / AGG_K;  // 100000
  const int blocks  = 2048;                 // 8 blocks/CU, persistent slots
  const int nslots  = blocks * 256 / 32;    // 16384 slots, ~6 nodes each

  Aggregator_26439818674919_kernel<<<blocks, 256, 0, stream>>>(
      weight, nidx, out, n_nodes, nslots);
}

// Round 7
// 152.699 us; speedup vs baseline: 1.0297x; 1.0297x over previous
//
#include <hip/hip_runtime.h>

// Mean aggregator: out[n,:] = (1/K) * sum_k weight[idx[n,k],:]
// N = 100000 nodes, K = 10 neighbors, D = 128 feat (fp32).
//
// R7: request-granularity falsification. Previous layout: 32 lanes/node,
// one wave instruction touches 2 rows (8 discontiguous 128B lines).
// This layout: 64 lanes/node (one full wave per row-gather), float2 per
// lane -> each VMEM instruction reads ONE contiguous 512B row (4 lines).
// Halves the discontiguous-segment count per instruction at identical
// byte traffic. Tests whether the ~77us plateau is coalescer/request
// overhead (win) or fabric byte service rate (flat -> roofline).

#define AGG_K 10
#define AGG_D 128

typedef float f32x2 __attribute__((ext_vector_type(2)));

__global__ __launch_bounds__(256) void Aggregator_26439818674919_kernel(
    const float* __restrict__ weight,
    const int* __restrict__ nidx,
    float* __restrict__ out,
    int n_nodes) {
  const int tid  = blockIdx.x * 256 + threadIdx.x;
  const int node = tid >> 6;   // one full wave (64 lanes) per node
  const int lane = tid & 63;   // lane*2 floats within the 128-float row
  if (node >= n_nodes) return;

  const int ibase = node * AGG_K;
  const unsigned lane_off = (unsigned)(lane * 2);

  // Wave-uniform index loads (same addr across 64 lanes -> broadcast).
  int idx[AGG_K];
#pragma unroll
  for (int k = 0; k < AGG_K; ++k) idx[k] = nidx[ibase + k];

  f32x2 acc = {0.f, 0.f};
#pragma unroll
  for (int k = 0; k < AGG_K; ++k) {
    const f32x2 v = *reinterpret_cast<const f32x2*>(
        &weight[(unsigned)idx[k] * AGG_D + lane_off]);
    acc += v;
  }
  acc *= (1.0f / AGG_K);
  *reinterpret_cast<f32x2*>(&out[(size_t)node * AGG_D + lane_off]) = acc;
}

extern "C" void kernel_launch(void* const* d_in, const int* in_sizes, int n_in,
                              void* d_out, int out_size, void* d_ws, size_t ws_size,
                              hipStream_t stream) {
  const float* weight = (const float*)d_in[0];
  const int*   nidx   = (const int*)d_in[1];
  float*       out    = (float*)d_out;

  const int n_nodes = in_sizes[1] / AGG_K;          // 100000
  const int total_threads = n_nodes * 64;           // 64 lanes per node
  const int blocks = (total_threads + 255) / 256;   // 25000

  Aggregator_26439818674919_kernel<<<blocks, 256, 0, stream>>>(
      weight, nidx, out, n_nodes);
}